// Round 14
// baseline (295.389 us; speedup 1.0000x reference)
//
#include <hip/hip_runtime.h>
#include <stdint.h>

#define N_NODES 10000
#define M_PAD   10112    // 79 * 128
#define N_EDGES 160000
#define DIM     512
#define N_ELEMS 5120000  // N_NODES*DIM
#define NEG_SLOPE 0.25f
#define ELL_W   64       // max degree slack: E[deg]=16, P(deg>64) ~ 1e-19

typedef short          short8   __attribute__((ext_vector_type(8)));
typedef unsigned short ushort8v __attribute__((ext_vector_type(8)));
typedef __bf16         bf16x8   __attribute__((ext_vector_type(8)));
typedef float          f32x4    __attribute__((ext_vector_type(4)));

__device__ __forceinline__ unsigned short f2bf(float f) {   // RNE f32->bf16
    uint32_t u = __builtin_bit_cast(uint32_t, f);
    uint32_t r = (u + 0x7fffu + ((u >> 16) & 1u)) >> 16;
    return (unsigned short)r;
}
__device__ __forceinline__ float b2f(unsigned short u) {
    return __builtin_bit_cast(float, (uint32_t)u << 16);
}

// ---------------- threefry2x32-20, key = jax.random.key(42) = (0, 42) ----------------
__device__ __forceinline__ uint32_t rotl32(uint32_t x, uint32_t d) {
    return (x << d) | (x >> (32u - d));
}
__device__ __forceinline__ void threefry_42(uint32_t x0, uint32_t x1,
                                            uint32_t& o0, uint32_t& o1) {
    const uint32_t ks0 = 0u, ks1 = 42u, ks2 = 0x1BD11BDAu ^ 42u;
    x0 += ks0; x1 += ks1;
#define TF_R4(a,b,c,d) \
    x0 += x1; x1 = rotl32(x1,a); x1 ^= x0; \
    x0 += x1; x1 = rotl32(x1,b); x1 ^= x0; \
    x0 += x1; x1 = rotl32(x1,c); x1 ^= x0; \
    x0 += x1; x1 = rotl32(x1,d); x1 ^= x0;
    TF_R4(13,15,26,6);  x0 += ks1; x1 += ks2 + 1u;
    TF_R4(17,29,16,24); x0 += ks2; x1 += ks0 + 2u;
    TF_R4(13,15,26,6);  x0 += ks0; x1 += ks1 + 3u;
    TF_R4(17,29,16,24); x0 += ks1; x1 += ks2 + 4u;
    TF_R4(13,15,26,6);  x0 += ks2; x1 += ks0 + 5u;
#undef TF_R4
    o0 = x0; o1 = x1;
}

// ------- fused prep: convert H, transpose W1/W2, zero epack (ELL pads), zero deg+queues -------
#define CONV_BLKS 5000
#define TR_BLKS   64
#define EZ_BLKS   1250   // 10000*64 edge slots * 8B / (256 thr * 16B)
#define ZERO_BLKS 10     // covers N_NODES + 8 queue counters

__device__ __forceinline__ void transpose_tile(const float* __restrict__ W,
                                               unsigned short* __restrict__ WT,
                                               int tile, float (*ts)[65]) {
    int k0 = (tile & 7) * 64, n0 = (tile >> 3) * 64;
    int tx = threadIdx.x & 15, ty = threadIdx.x >> 4;
    #pragma unroll
    for (int i = 0; i < 4; ++i) {
        int k = i * 16 + ty;
        float4 v = *(const float4*)&W[(size_t)(k0 + k) * DIM + n0 + tx * 4];
        ts[k][tx * 4 + 0] = v.x; ts[k][tx * 4 + 1] = v.y;
        ts[k][tx * 4 + 2] = v.z; ts[k][tx * 4 + 3] = v.w;
    }
    __syncthreads();
    #pragma unroll
    for (int i = 0; i < 4; ++i) {
        int n = i * 16 + ty;
        ushort4 o;
        o.x = f2bf(ts[tx * 4 + 0][n]); o.y = f2bf(ts[tx * 4 + 1][n]);
        o.z = f2bf(ts[tx * 4 + 2][n]); o.w = f2bf(ts[tx * 4 + 3][n]);
        *(ushort4*)&WT[(size_t)(n0 + n) * DIM + k0 + tx * 4] = o;
    }
}

__global__ __launch_bounds__(256)
void prep_kernel(const float* __restrict__ H, const float* __restrict__ W1,
                 const float* __restrict__ W2, unsigned short* __restrict__ Abf,
                 unsigned short* __restrict__ WT1, unsigned short* __restrict__ WT2,
                 int4* __restrict__ epack4, int* __restrict__ deg) {
    __shared__ float ts[64][65];
    int b = blockIdx.x;
    if (b < CONV_BLKS) {
        int i = b * 256 + threadIdx.x;
        float4 v = ((const float4*)H)[i];
        ushort4 o;
        o.x = f2bf(v.x); o.y = f2bf(v.y); o.z = f2bf(v.z); o.w = f2bf(v.w);
        ((ushort4*)Abf)[i] = o;
    } else if (b < CONV_BLKS + TR_BLKS) {
        transpose_tile(W1, WT1, b - CONV_BLKS, ts);
    } else if (b < CONV_BLKS + 2 * TR_BLKS) {
        transpose_tile(W2, WT2, b - CONV_BLKS - TR_BLKS, ts);
    } else if (b < CONV_BLKS + 2 * TR_BLKS + EZ_BLKS) {
        int i = (b - CONV_BLKS - 2 * TR_BLKS) * 256 + threadIdx.x;
        epack4[i] = make_int4(0, 0, 0, 0);       // pad edges: col 0, val 0.0
    } else {
        int i = (b - CONV_BLKS - 2 * TR_BLKS - EZ_BLKS) * 1024 + threadIdx.x * 4;
        #pragma unroll
        for (int j = 0; j < 4; ++j)
            if (i + j < N_NODES + 8) deg[i + j] = 0;   // deg + 8 queue counters
    }
}

// ---------------- ELL build ----------------
__global__ void ell_scatter(const int* __restrict__ rows, const int* __restrict__ cols,
                            const float* __restrict__ vals, int* __restrict__ deg,
                            int2* __restrict__ epack) {
    int e = blockIdx.x * blockDim.x + threadIdx.x;
    if (e < N_EDGES) {
        int r = rows[e];
        int p = atomicAdd(&deg[r], 1);
        epack[(size_t)r * ELL_W + p] = make_int2(cols[e], __float_as_int(vals[e]));
    }
}

// ---------------- bf16 MFMA GEMM (unchanged r3 config): 128x128, BK=64 ----------------
__global__ __launch_bounds__(256)
void mfma_gemm(const unsigned short* __restrict__ A, const unsigned short* __restrict__ BT,
               unsigned short* __restrict__ C, int M) {
    __shared__ short8 As[1024];
    __shared__ short8 Bs[1024];
    int tid  = threadIdx.x;
    int wid  = tid >> 6, lane = tid & 63;
    int bm   = blockIdx.x * 128;
    int bn   = blockIdx.y * 128;
    int wm   = (wid >> 1) * 64, wn = (wid & 1) * 64;

    f32x4 acc[4][4] = {};
    int srow = lane >> 3;
    int sslot = lane & 7;

    for (int k0 = 0; k0 < DIM; k0 += 64) {
        #pragma unroll
        for (int c = 0; c < 4; ++c) {
            int chunk = wid * 4 + c;
            int r  = chunk * 8 + srow;
            int ks = sslot ^ (r & 7);
            const unsigned short* ga = A  + (size_t)(bm + r) * DIM + k0 + ks * 8;
            const unsigned short* gb = BT + (size_t)(bn + r) * DIM + k0 + ks * 8;
            __builtin_amdgcn_global_load_lds(
                (const __attribute__((address_space(1))) void*)ga,
                (__attribute__((address_space(3))) void*)&As[chunk * 64], 16, 0, 0);
            __builtin_amdgcn_global_load_lds(
                (const __attribute__((address_space(1))) void*)gb,
                (__attribute__((address_space(3))) void*)&Bs[chunk * 64], 16, 0, 0);
        }
        __syncthreads();

        int lrow = lane & 15;
        int kgrp = lane >> 4;
        #pragma unroll
        for (int ks = 0; ks < 2; ++ks) {
            short8 af[4], bfr[4];
            #pragma unroll
            for (int i = 0; i < 4; ++i) {
                int r = wm + i * 16 + lrow;
                af[i]  = As[r * 8 + ((ks * 4 + kgrp) ^ (r & 7))];
                int n = wn + i * 16 + lrow;
                bfr[i] = Bs[n * 8 + ((ks * 4 + kgrp) ^ (n & 7))];
            }
            #pragma unroll
            for (int i = 0; i < 4; ++i)
                #pragma unroll
                for (int j = 0; j < 4; ++j)
                    acc[i][j] = __builtin_amdgcn_mfma_f32_16x16x32_bf16(
                        __builtin_bit_cast(bf16x8, af[i]),
                        __builtin_bit_cast(bf16x8, bfr[j]), acc[i][j], 0, 0, 0);
        }
        __syncthreads();
    }

    int crow = (lane >> 4) * 4;
    int ccol = lane & 15;
    #pragma unroll
    for (int i = 0; i < 4; ++i) {
        #pragma unroll
        for (int r = 0; r < 4; ++r) {
            int row = bm + wm + i * 16 + crow + r;
            if (row < M) {
                size_t base = (size_t)row * DIM + bn + wn + ccol;
                #pragma unroll
                for (int j = 0; j < 4; ++j)
                    C[base + j * 16] = f2bf(acc[i][j][r]);
            }
        }
    }
}

// ---------------- SpMM v9: TRUE XCD pinning via s_getreg(HW_REG_XCC_ID) + work queue ----
// v8's gather body. Quarter assignment no longer assumes blockIdx%8->XCD: each block
// reads its REAL XCD id (hwreg 20, bits[3:0] — m09-verified 0..7) and pops a row-group
// from the per-quarter atomic queue. Pigeonhole (blocks == items, one item per block)
// guarantees full coverage regardless of XCD distribution; the register read is purely
// a locality hint. Per-XCD-pair X working set = 2.5MB < 4MB L2 -> resident.
#define ACC2(v, U) \
    acc0 = fmaf(v, __builtin_bit_cast(float, (U) << 16), acc0); \
    acc1 = fmaf(v, __builtin_bit_cast(float, (U) & 0xffff0000u), acc1);

template <int LAYER>
__global__ __launch_bounds__(256)
void spmm_kernel(const unsigned short* __restrict__ X, const int* __restrict__ deg,
                 const int2* __restrict__ epack, const float* __restrict__ bias,
                 void* __restrict__ outp, int* __restrict__ qcur) {
    __shared__ int s_item;
    if (threadIdx.x == 0) {
        uint32_t xcc = __builtin_amdgcn_s_getreg(6164);   // hwreg(id=20,off=0,size=4)
        int q0 = (int)((xcc >> 1) & 3);                   // XCD pair -> quarter
        int it = -1;
        #pragma unroll
        for (int t = 0; t < 4; ++t) {
            int qq = (q0 + t) & 3;
            int i = atomicAdd(&qcur[qq], 1);
            if (i < N_NODES / 4) { it = (i << 2) | qq; break; }
        }
        s_item = it;
    }
    __syncthreads();
    int item = s_item;
    if (item < 0) return;                        // unreachable (pigeonhole)
    int q    = item & 3;                         // quarter of D
    int row  = (item >> 2) * 4 + (threadIdx.x >> 6);
    int lane = threadIdx.x & 63;
    int d  = deg[row];
    int dp = (d + 7) & ~7;                       // padded degree (pads are zero edges)
    const int2* ep = epack + (size_t)row * ELL_W;
    const uint32_t* X2 = (const uint32_t*)X;     // ushort2 units; row stride = 256
    uint32_t qoff = q * 64 + lane;               // this lane's 4B chunk of the quarter

    float acc0 = 0.f, acc1 = 0.f;
    int base = 0;
    for (; base + 16 <= dp; base += 16) {        // 16 gathers in flight
        int4 eA = *(const int4*)(ep + base);
        int4 eB = *(const int4*)(ep + base + 2);
        int4 eC = *(const int4*)(ep + base + 4);
        int4 eD = *(const int4*)(ep + base + 6);
        int4 eE = *(const int4*)(ep + base + 8);
        int4 eF = *(const int4*)(ep + base + 10);
        int4 eG = *(const int4*)(ep + base + 12);
        int4 eH = *(const int4*)(ep + base + 14);
        uint32_t x0 = X2[(size_t)eA.x * 256 + qoff];
        uint32_t x1 = X2[(size_t)eA.z * 256 + qoff];
        uint32_t x2 = X2[(size_t)eB.x * 256 + qoff];
        uint32_t x3 = X2[(size_t)eB.z * 256 + qoff];
        uint32_t x4 = X2[(size_t)eC.x * 256 + qoff];
        uint32_t x5 = X2[(size_t)eC.z * 256 + qoff];
        uint32_t x6 = X2[(size_t)eD.x * 256 + qoff];
        uint32_t x7 = X2[(size_t)eD.z * 256 + qoff];
        uint32_t x8 = X2[(size_t)eE.x * 256 + qoff];
        uint32_t x9 = X2[(size_t)eE.z * 256 + qoff];
        uint32_t xa = X2[(size_t)eF.x * 256 + qoff];
        uint32_t xb = X2[(size_t)eF.z * 256 + qoff];
        uint32_t xc = X2[(size_t)eG.x * 256 + qoff];
        uint32_t xd = X2[(size_t)eG.z * 256 + qoff];
        uint32_t xe = X2[(size_t)eH.x * 256 + qoff];
        uint32_t xf = X2[(size_t)eH.z * 256 + qoff];
        float v0 = __int_as_float(eA.y), v1 = __int_as_float(eA.w);
        float v2 = __int_as_float(eB.y), v3 = __int_as_float(eB.w);
        float v4 = __int_as_float(eC.y), v5 = __int_as_float(eC.w);
        float v6 = __int_as_float(eD.y), v7 = __int_as_float(eD.w);
        float v8 = __int_as_float(eE.y), v9 = __int_as_float(eE.w);
        float va = __int_as_float(eF.y), vb = __int_as_float(eF.w);
        float vc = __int_as_float(eG.y), vd = __int_as_float(eG.w);
        float ve = __int_as_float(eH.y), vf = __int_as_float(eH.w);
        ACC2(v0, x0) ACC2(v1, x1) ACC2(v2, x2) ACC2(v3, x3)
        ACC2(v4, x4) ACC2(v5, x5) ACC2(v6, x6) ACC2(v7, x7)
        ACC2(v8, x8) ACC2(v9, x9) ACC2(va, xa) ACC2(vb, xb)
        ACC2(vc, xc) ACC2(vd, xd) ACC2(ve, xe) ACC2(vf, xf)
    }
    if (base < dp) {                             // exactly one 8-edge chunk
        int4 eA = *(const int4*)(ep + base);
        int4 eB = *(const int4*)(ep + base + 2);
        int4 eC = *(const int4*)(ep + base + 4);
        int4 eD = *(const int4*)(ep + base + 6);
        uint32_t x0 = X2[(size_t)eA.x * 256 + qoff];
        uint32_t x1 = X2[(size_t)eA.z * 256 + qoff];
        uint32_t x2 = X2[(size_t)eB.x * 256 + qoff];
        uint32_t x3 = X2[(size_t)eB.z * 256 + qoff];
        uint32_t x4 = X2[(size_t)eC.x * 256 + qoff];
        uint32_t x5 = X2[(size_t)eC.z * 256 + qoff];
        uint32_t x6 = X2[(size_t)eD.x * 256 + qoff];
        uint32_t x7 = X2[(size_t)eD.z * 256 + qoff];
        float v0 = __int_as_float(eA.y), v1 = __int_as_float(eA.w);
        float v2 = __int_as_float(eB.y), v3 = __int_as_float(eB.w);
        float v4 = __int_as_float(eC.y), v5 = __int_as_float(eC.w);
        float v6 = __int_as_float(eD.y), v7 = __int_as_float(eD.w);
        ACC2(v0, x0) ACC2(v1, x1) ACC2(v2, x2) ACC2(v3, x3)
        ACC2(v4, x4) ACC2(v5, x5) ACC2(v6, x6) ACC2(v7, x7)
    }

    float2 bi = ((const float2*)bias)[q * 64 + lane];
    float r0 = acc0 + bi.x, r1 = acc1 + bi.y;
    r0 = (r0 >= 0.f) ? r0 : NEG_SLOPE * r0;
    r1 = (r1 >= 0.f) ? r1 : NEG_SLOPE * r1;
    if (LAYER == 1) {
        uint32_t e0 = (uint32_t)row * DIM + q * 128 + lane * 2;
        uint32_t o0, o1;
        threefry_42(0u, e0, o0, o1);             // partitionable: bits=o0^o1, keep iff MSB clear
        uint32_t bits0 = o0 ^ o1;
        threefry_42(0u, e0 + 1, o0, o1);
        uint32_t bits1 = o0 ^ o1;
        float w0 = ((int)bits0 >= 0) ? r0 * 2.0f : 0.0f;
        float w1 = ((int)bits1 >= 0) ? r1 * 2.0f : 0.0f;
        uint32_t o = (uint32_t)f2bf(w0) | ((uint32_t)f2bf(w1) << 16);
        ((uint32_t*)outp)[(size_t)row * 256 + q * 64 + lane] = o;
    } else {
        float2 o = make_float2(r0, r1);
        ((float2*)outp)[(size_t)row * 256 + q * 64 + lane] = o;
    }
}

// ---------------- launch ----------------
extern "C" void kernel_launch(void* const* d_in, const int* in_sizes, int n_in,
                              void* d_out, int out_size, void* d_ws, size_t ws_size,
                              hipStream_t stream) {
    const float* H    = (const float*)d_in[0];
    const int*   rows = (const int*)  d_in[1];
    const int*   cols = (const int*)  d_in[2];
    const float* vals = (const float*)d_in[3];
    const float* W1   = (const float*)d_in[4];
    const float* b1   = (const float*)d_in[5];
    const float* W2   = (const float*)d_in[6];
    const float* b2   = (const float*)d_in[7];
    float* out = (float*)d_out;

    char* ws = (char*)d_ws;
    size_t off = 0;
    auto alloc = [&](size_t bytes) -> void* {
        off = (off + 255) & ~(size_t)255;
        void* p = ws + off;
        off += bytes;
        return p;
    };
    int*  deg   = (int*) alloc((size_t)(N_NODES + 8) * 4);     // + 8 queue counters
    int*  qcurA = deg + N_NODES;                               // spmm1 queues [4]
    int*  qcurB = deg + N_NODES + 4;                           // spmm2 queues [4]
    int2* epack = (int2*)alloc((size_t)N_NODES * ELL_W * 8);   // 5.12 MB ELL
    unsigned short* WT1 = (unsigned short*)alloc((size_t)DIM * DIM * 2);
    unsigned short* WT2 = (unsigned short*)alloc((size_t)DIM * DIM * 2);
    unsigned short* Abf = (unsigned short*)alloc((size_t)M_PAD * DIM * 2);
    unsigned short* hbf = (unsigned short*)alloc((size_t)M_PAD * DIM * 2);
    unsigned short* Xbf = (unsigned short*)alloc((size_t)N_NODES * DIM * 2);

    int prep_blocks = CONV_BLKS + 2 * TR_BLKS + EZ_BLKS + ZERO_BLKS;
    prep_kernel<<<prep_blocks, 256, 0, stream>>>(H, W1, W2, Abf, WT1, WT2,
                                                 (int4*)epack, deg);
    ell_scatter<<<(N_EDGES + 255) / 256, 256, 0, stream>>>(rows, cols, vals, deg, epack);

    dim3 ggrid(M_PAD / 128, DIM / 128);
    mfma_gemm<<<ggrid, 256, 0, stream>>>(Abf, WT1, Xbf, N_NODES);
    spmm_kernel<1><<<N_NODES, 256, 0, stream>>>(Xbf, deg, epack, b1, hbf, qcurA);
    mfma_gemm<<<ggrid, 256, 0, stream>>>(hbf, WT2, Xbf, N_NODES);
    spmm_kernel<2><<<N_NODES, 256, 0, stream>>>(Xbf, deg, epack, b2, out, qcurB);
}

// Round 15
// 102.235 us; speedup vs baseline: 2.8893x; 2.8893x over previous
//
#include <hip/hip_runtime.h>
#include <stdint.h>

#define N_NODES 10000
#define M_PAD   10112    // 79 * 128
#define N_EDGES 160000
#define DIM     512
#define N_ELEMS 5120000  // N_NODES*DIM
#define NEG_SLOPE 0.25f
#define ELL_W   64       // max degree slack: E[deg]=16, P(deg>64) ~ 1e-19

typedef short          short8   __attribute__((ext_vector_type(8)));
typedef unsigned short ushort8v __attribute__((ext_vector_type(8)));
typedef __bf16         bf16x8   __attribute__((ext_vector_type(8)));
typedef float          f32x4    __attribute__((ext_vector_type(4)));

__device__ __forceinline__ unsigned short f2bf(float f) {   // RNE f32->bf16
    uint32_t u = __builtin_bit_cast(uint32_t, f);
    uint32_t r = (u + 0x7fffu + ((u >> 16) & 1u)) >> 16;
    return (unsigned short)r;
}
__device__ __forceinline__ float b2f(unsigned short u) {
    return __builtin_bit_cast(float, (uint32_t)u << 16);
}

// ---------------- threefry2x32-20, key = jax.random.key(42) = (0, 42) ----------------
__device__ __forceinline__ uint32_t rotl32(uint32_t x, uint32_t d) {
    return (x << d) | (x >> (32u - d));
}
__device__ __forceinline__ void threefry_42(uint32_t x0, uint32_t x1,
                                            uint32_t& o0, uint32_t& o1) {
    const uint32_t ks0 = 0u, ks1 = 42u, ks2 = 0x1BD11BDAu ^ 42u;
    x0 += ks0; x1 += ks1;
#define TF_R4(a,b,c,d) \
    x0 += x1; x1 = rotl32(x1,a); x1 ^= x0; \
    x0 += x1; x1 = rotl32(x1,b); x1 ^= x0; \
    x0 += x1; x1 = rotl32(x1,c); x1 ^= x0; \
    x0 += x1; x1 = rotl32(x1,d); x1 ^= x0;
    TF_R4(13,15,26,6);  x0 += ks1; x1 += ks2 + 1u;
    TF_R4(17,29,16,24); x0 += ks2; x1 += ks0 + 2u;
    TF_R4(13,15,26,6);  x0 += ks0; x1 += ks1 + 3u;
    TF_R4(17,29,16,24); x0 += ks1; x1 += ks2 + 4u;
    TF_R4(13,15,26,6);  x0 += ks2; x1 += ks0 + 5u;
#undef TF_R4
    o0 = x0; o1 = x1;
}

// ------- fused prep: convert H, transpose W1/W2, zero epack (ELL pads), zero deg -------
#define CONV_BLKS 5000
#define TR_BLKS   64
#define EZ_BLKS   1250   // 10000*64 edge slots * 8B / (256 thr * 16B)
#define ZERO_BLKS 10

__device__ __forceinline__ void transpose_tile(const float* __restrict__ W,
                                               unsigned short* __restrict__ WT,
                                               int tile, float (*ts)[65]) {
    int k0 = (tile & 7) * 64, n0 = (tile >> 3) * 64;
    int tx = threadIdx.x & 15, ty = threadIdx.x >> 4;
    #pragma unroll
    for (int i = 0; i < 4; ++i) {
        int k = i * 16 + ty;
        float4 v = *(const float4*)&W[(size_t)(k0 + k) * DIM + n0 + tx * 4];
        ts[k][tx * 4 + 0] = v.x; ts[k][tx * 4 + 1] = v.y;
        ts[k][tx * 4 + 2] = v.z; ts[k][tx * 4 + 3] = v.w;
    }
    __syncthreads();
    #pragma unroll
    for (int i = 0; i < 4; ++i) {
        int n = i * 16 + ty;
        ushort4 o;
        o.x = f2bf(ts[tx * 4 + 0][n]); o.y = f2bf(ts[tx * 4 + 1][n]);
        o.z = f2bf(ts[tx * 4 + 2][n]); o.w = f2bf(ts[tx * 4 + 3][n]);
        *(ushort4*)&WT[(size_t)(n0 + n) * DIM + k0 + tx * 4] = o;
    }
}

__global__ __launch_bounds__(256)
void prep_kernel(const float* __restrict__ H, const float* __restrict__ W1,
                 const float* __restrict__ W2, unsigned short* __restrict__ Abf,
                 unsigned short* __restrict__ WT1, unsigned short* __restrict__ WT2,
                 int4* __restrict__ epack4, int* __restrict__ deg) {
    __shared__ float ts[64][65];
    int b = blockIdx.x;
    if (b < CONV_BLKS) {
        int i = b * 256 + threadIdx.x;
        float4 v = ((const float4*)H)[i];
        ushort4 o;
        o.x = f2bf(v.x); o.y = f2bf(v.y); o.z = f2bf(v.z); o.w = f2bf(v.w);
        ((ushort4*)Abf)[i] = o;
    } else if (b < CONV_BLKS + TR_BLKS) {
        transpose_tile(W1, WT1, b - CONV_BLKS, ts);
    } else if (b < CONV_BLKS + 2 * TR_BLKS) {
        transpose_tile(W2, WT2, b - CONV_BLKS - TR_BLKS, ts);
    } else if (b < CONV_BLKS + 2 * TR_BLKS + EZ_BLKS) {
        int i = (b - CONV_BLKS - 2 * TR_BLKS) * 256 + threadIdx.x;
        epack4[i] = make_int4(0, 0, 0, 0);       // pad edges: col 0, val 0.0
    } else {
        int i = (b - CONV_BLKS - 2 * TR_BLKS - EZ_BLKS) * 1024 + threadIdx.x * 4;
        #pragma unroll
        for (int j = 0; j < 4; ++j)
            if (i + j < N_NODES) deg[i + j] = 0;
    }
}

// ---------------- ELL build ----------------
__global__ void ell_scatter(const int* __restrict__ rows, const int* __restrict__ cols,
                            const float* __restrict__ vals, int* __restrict__ deg,
                            int2* __restrict__ epack) {
    int e = blockIdx.x * blockDim.x + threadIdx.x;
    if (e < N_EDGES) {
        int r = rows[e];
        int p = atomicAdd(&deg[r], 1);
        epack[(size_t)r * ELL_W + p] = make_int2(cols[e], __float_as_int(vals[e]));
    }
}

// ---------------- bf16 MFMA GEMM (r3 config): 128x128, BK=64 ----------------
__global__ __launch_bounds__(256)
void mfma_gemm(const unsigned short* __restrict__ A, const unsigned short* __restrict__ BT,
               unsigned short* __restrict__ C, int M) {
    __shared__ short8 As[1024];
    __shared__ short8 Bs[1024];
    int tid  = threadIdx.x;
    int wid  = tid >> 6, lane = tid & 63;
    int bm   = blockIdx.x * 128;
    int bn   = blockIdx.y * 128;
    int wm   = (wid >> 1) * 64, wn = (wid & 1) * 64;

    f32x4 acc[4][4] = {};
    int srow = lane >> 3;
    int sslot = lane & 7;

    for (int k0 = 0; k0 < DIM; k0 += 64) {
        #pragma unroll
        for (int c = 0; c < 4; ++c) {
            int chunk = wid * 4 + c;
            int r  = chunk * 8 + srow;
            int ks = sslot ^ (r & 7);
            const unsigned short* ga = A  + (size_t)(bm + r) * DIM + k0 + ks * 8;
            const unsigned short* gb = BT + (size_t)(bn + r) * DIM + k0 + ks * 8;
            __builtin_amdgcn_global_load_lds(
                (const __attribute__((address_space(1))) void*)ga,
                (__attribute__((address_space(3))) void*)&As[chunk * 64], 16, 0, 0);
            __builtin_amdgcn_global_load_lds(
                (const __attribute__((address_space(1))) void*)gb,
                (__attribute__((address_space(3))) void*)&Bs[chunk * 64], 16, 0, 0);
        }
        __syncthreads();

        int lrow = lane & 15;
        int kgrp = lane >> 4;
        #pragma unroll
        for (int ks = 0; ks < 2; ++ks) {
            short8 af[4], bfr[4];
            #pragma unroll
            for (int i = 0; i < 4; ++i) {
                int r = wm + i * 16 + lrow;
                af[i]  = As[r * 8 + ((ks * 4 + kgrp) ^ (r & 7))];
                int n = wn + i * 16 + lrow;
                bfr[i] = Bs[n * 8 + ((ks * 4 + kgrp) ^ (n & 7))];
            }
            #pragma unroll
            for (int i = 0; i < 4; ++i)
                #pragma unroll
                for (int j = 0; j < 4; ++j)
                    acc[i][j] = __builtin_amdgcn_mfma_f32_16x16x32_bf16(
                        __builtin_bit_cast(bf16x8, af[i]),
                        __builtin_bit_cast(bf16x8, bfr[j]), acc[i][j], 0, 0, 0);
        }
        __syncthreads();
    }

    int crow = (lane >> 4) * 4;
    int ccol = lane & 15;
    #pragma unroll
    for (int i = 0; i < 4; ++i) {
        #pragma unroll
        for (int r = 0; r < 4; ++r) {
            int row = bm + wm + i * 16 + crow + r;
            if (row < M) {
                size_t base = (size_t)row * DIM + bn + wn + ccol;
                #pragma unroll
                for (int j = 0; j < 4; ++j)
                    C[base + j * 16] = f2bf(acc[i][j][r]);
            }
        }
    }
}

// ---------------- SpMM v5 (r8 exact): one wave/row, 16 gathers in flight ----------------
template <int LAYER>
__global__ __launch_bounds__(256)
void spmm_kernel(const unsigned short* __restrict__ X, const int* __restrict__ deg,
                 const int2* __restrict__ epack, const float* __restrict__ bias,
                 void* __restrict__ outp) {
    int row  = blockIdx.x * 4 + (threadIdx.x >> 6);
    int lane = threadIdx.x & 63;
    int d  = deg[row];
    int dp = (d + 7) & ~7;                       // padded degree (pads are zero edges)
    const int2* ep = epack + (size_t)row * ELL_W;
    const ushort8v* X8 = (const ushort8v*)X;     // row stride = 64 ushort8

    float acc[8] = {};
    int base = 0;
    for (; base + 16 <= dp; base += 16) {        // 16 gathers in flight
        int4 eA = *(const int4*)(ep + base);
        int4 eB = *(const int4*)(ep + base + 2);
        int4 eC = *(const int4*)(ep + base + 4);
        int4 eD = *(const int4*)(ep + base + 6);
        int4 eE = *(const int4*)(ep + base + 8);
        int4 eF = *(const int4*)(ep + base + 10);
        int4 eG = *(const int4*)(ep + base + 12);
        int4 eH = *(const int4*)(ep + base + 14);
        ushort8v x0 = X8[(size_t)eA.x * 64 + lane];
        ushort8v x1 = X8[(size_t)eA.z * 64 + lane];
        ushort8v x2 = X8[(size_t)eB.x * 64 + lane];
        ushort8v x3 = X8[(size_t)eB.z * 64 + lane];
        ushort8v x4 = X8[(size_t)eC.x * 64 + lane];
        ushort8v x5 = X8[(size_t)eC.z * 64 + lane];
        ushort8v x6 = X8[(size_t)eD.x * 64 + lane];
        ushort8v x7 = X8[(size_t)eD.z * 64 + lane];
        ushort8v x8 = X8[(size_t)eE.x * 64 + lane];
        ushort8v x9 = X8[(size_t)eE.z * 64 + lane];
        ushort8v xa = X8[(size_t)eF.x * 64 + lane];
        ushort8v xb = X8[(size_t)eF.z * 64 + lane];
        ushort8v xc = X8[(size_t)eG.x * 64 + lane];
        ushort8v xd = X8[(size_t)eG.z * 64 + lane];
        ushort8v xe = X8[(size_t)eH.x * 64 + lane];
        ushort8v xf = X8[(size_t)eH.z * 64 + lane];
        float v0 = __int_as_float(eA.y), v1 = __int_as_float(eA.w);
        float v2 = __int_as_float(eB.y), v3 = __int_as_float(eB.w);
        float v4 = __int_as_float(eC.y), v5 = __int_as_float(eC.w);
        float v6 = __int_as_float(eD.y), v7 = __int_as_float(eD.w);
        float v8 = __int_as_float(eE.y), v9 = __int_as_float(eE.w);
        float va = __int_as_float(eF.y), vb = __int_as_float(eF.w);
        float vc = __int_as_float(eG.y), vd = __int_as_float(eG.w);
        float ve = __int_as_float(eH.y), vf = __int_as_float(eH.w);
        #pragma unroll
        for (int j = 0; j < 8; ++j) {
            acc[j] = fmaf(v0, b2f(x0[j]), acc[j]);
            acc[j] = fmaf(v1, b2f(x1[j]), acc[j]);
            acc[j] = fmaf(v2, b2f(x2[j]), acc[j]);
            acc[j] = fmaf(v3, b2f(x3[j]), acc[j]);
            acc[j] = fmaf(v4, b2f(x4[j]), acc[j]);
            acc[j] = fmaf(v5, b2f(x5[j]), acc[j]);
            acc[j] = fmaf(v6, b2f(x6[j]), acc[j]);
            acc[j] = fmaf(v7, b2f(x7[j]), acc[j]);
            acc[j] = fmaf(v8, b2f(x8[j]), acc[j]);
            acc[j] = fmaf(v9, b2f(x9[j]), acc[j]);
            acc[j] = fmaf(va, b2f(xa[j]), acc[j]);
            acc[j] = fmaf(vb, b2f(xb[j]), acc[j]);
            acc[j] = fmaf(vc, b2f(xc[j]), acc[j]);
            acc[j] = fmaf(vd, b2f(xd[j]), acc[j]);
            acc[j] = fmaf(ve, b2f(xe[j]), acc[j]);
            acc[j] = fmaf(vf, b2f(xf[j]), acc[j]);
        }
    }
    if (base < dp) {                             // exactly one 8-edge chunk
        int4 eA = *(const int4*)(ep + base);
        int4 eB = *(const int4*)(ep + base + 2);
        int4 eC = *(const int4*)(ep + base + 4);
        int4 eD = *(const int4*)(ep + base + 6);
        ushort8v x0 = X8[(size_t)eA.x * 64 + lane];
        ushort8v x1 = X8[(size_t)eA.z * 64 + lane];
        ushort8v x2 = X8[(size_t)eB.x * 64 + lane];
        ushort8v x3 = X8[(size_t)eB.z * 64 + lane];
        ushort8v x4 = X8[(size_t)eC.x * 64 + lane];
        ushort8v x5 = X8[(size_t)eC.z * 64 + lane];
        ushort8v x6 = X8[(size_t)eD.x * 64 + lane];
        ushort8v x7 = X8[(size_t)eD.z * 64 + lane];
        float v0 = __int_as_float(eA.y), v1 = __int_as_float(eA.w);
        float v2 = __int_as_float(eB.y), v3 = __int_as_float(eB.w);
        float v4 = __int_as_float(eC.y), v5 = __int_as_float(eC.w);
        float v6 = __int_as_float(eD.y), v7 = __int_as_float(eD.w);
        #pragma unroll
        for (int j = 0; j < 8; ++j) {
            acc[j] = fmaf(v0, b2f(x0[j]), acc[j]);
            acc[j] = fmaf(v1, b2f(x1[j]), acc[j]);
            acc[j] = fmaf(v2, b2f(x2[j]), acc[j]);
            acc[j] = fmaf(v3, b2f(x3[j]), acc[j]);
            acc[j] = fmaf(v4, b2f(x4[j]), acc[j]);
            acc[j] = fmaf(v5, b2f(x5[j]), acc[j]);
            acc[j] = fmaf(v6, b2f(x6[j]), acc[j]);
            acc[j] = fmaf(v7, b2f(x7[j]), acc[j]);
        }
    }

    float4 bi0 = ((const float4*)bias)[lane * 2];
    float4 bi1 = ((const float4*)bias)[lane * 2 + 1];
    float bb[8] = { bi0.x, bi0.y, bi0.z, bi0.w, bi1.x, bi1.y, bi1.z, bi1.w };
    float r[8];
    #pragma unroll
    for (int j = 0; j < 8; ++j) {
        float v = acc[j] + bb[j];
        r[j] = (v >= 0.f) ? v : NEG_SLOPE * v;
    }
    if (LAYER == 1) {
        uint32_t e0 = (uint32_t)row * DIM + lane * 8;
        ushort8v o;
        #pragma unroll
        for (int j = 0; j < 8; ++j) {
            uint32_t o0, o1;
            threefry_42(0u, e0 + j, o0, o1);     // partitionable: bits=o0^o1, keep iff MSB clear
            uint32_t bits = o0 ^ o1;
            float v = ((int)bits >= 0) ? r[j] * 2.0f : 0.0f;
            o[j] = f2bf(v);
        }
        ((ushort8v*)outp)[(size_t)row * 64 + lane] = o;
    } else {
        float4 o0 = make_float4(r[0], r[1], r[2], r[3]);
        float4 o1 = make_float4(r[4], r[5], r[6], r[7]);
        ((float4*)outp)[(size_t)row * 128 + lane * 2]     = o0;
        ((float4*)outp)[(size_t)row * 128 + lane * 2 + 1] = o1;
    }
}

// ---------------- launch ----------------
extern "C" void kernel_launch(void* const* d_in, const int* in_sizes, int n_in,
                              void* d_out, int out_size, void* d_ws, size_t ws_size,
                              hipStream_t stream) {
    const float* H    = (const float*)d_in[0];
    const int*   rows = (const int*)  d_in[1];
    const int*   cols = (const int*)  d_in[2];
    const float* vals = (const float*)d_in[3];
    const float* W1   = (const float*)d_in[4];
    const float* b1   = (const float*)d_in[5];
    const float* W2   = (const float*)d_in[6];
    const float* b2   = (const float*)d_in[7];
    float* out = (float*)d_out;

    char* ws = (char*)d_ws;
    size_t off = 0;
    auto alloc = [&](size_t bytes) -> void* {
        off = (off + 255) & ~(size_t)255;
        void* p = ws + off;
        off += bytes;
        return p;
    };
    int*  deg   = (int*) alloc((size_t)N_NODES * 4);
    int2* epack = (int2*)alloc((size_t)N_NODES * ELL_W * 8);   // 5.12 MB ELL
    unsigned short* WT1 = (unsigned short*)alloc((size_t)DIM * DIM * 2);
    unsigned short* WT2 = (unsigned short*)alloc((size_t)DIM * DIM * 2);
    unsigned short* Abf = (unsigned short*)alloc((size_t)M_PAD * DIM * 2);
    unsigned short* hbf = (unsigned short*)alloc((size_t)M_PAD * DIM * 2);
    unsigned short* Xbf = (unsigned short*)alloc((size_t)N_NODES * DIM * 2);

    int prep_blocks = CONV_BLKS + 2 * TR_BLKS + EZ_BLKS + ZERO_BLKS;
    prep_kernel<<<prep_blocks, 256, 0, stream>>>(H, W1, W2, Abf, WT1, WT2,
                                                 (int4*)epack, deg);
    ell_scatter<<<(N_EDGES + 255) / 256, 256, 0, stream>>>(rows, cols, vals, deg, epack);

    dim3 ggrid(M_PAD / 128, DIM / 128);
    mfma_gemm<<<ggrid, 256, 0, stream>>>(Abf, WT1, Xbf, N_NODES);
    spmm_kernel<1><<<N_NODES / 4, 256, 0, stream>>>(Xbf, deg, epack, b1, hbf);
    mfma_gemm<<<ggrid, 256, 0, stream>>>(hbf, WT2, Xbf, N_NODES);
    spmm_kernel<2><<<N_NODES / 4, 256, 0, stream>>>(Xbf, deg, epack, b2, out);
}